// Round 6
// baseline (211.321 us; speedup 1.0000x reference)
//
#include <hip/hip_runtime.h>
#include <hip/hip_bf16.h>
#include <cstddef>
#include <cmath>

// Problem constants: B=4, N=1024, H=16, hd=64, EMB=1024, M=B*N=4096
// split order in reference: K, Q, V (cols 0..1023 = K, 1024..2047 = Q, 2048.. = V)

typedef _Float16 f16x4 __attribute__((ext_vector_type(4)));
typedef _Float16 f16x8 __attribute__((ext_vector_type(8)));
typedef float    f32x4 __attribute__((ext_vector_type(4)));

#define LOG2E 1.4426950408889634f

// async global->LDS, 16B per lane. LDS dest: wave-uniform base + lane*16.
__device__ __forceinline__ void gload_lds16(const void* g, void* l) {
    __builtin_amdgcn_global_load_lds(
        (const __attribute__((address_space(1))) unsigned int*)g,
        (__attribute__((address_space(3))) unsigned int*)l, 16, 0, 0);
}

// ---------------------------------------------------------------------------
// fp32 -> f16 elementwise convert (vectorized 8/thread)
__global__ __launch_bounds__(256) void cvt_f32_f16(
    const float* __restrict__ in, _Float16* __restrict__ out, int n8)
{
    int i = blockIdx.x * 256 + threadIdx.x;
    if (i < n8) {
        const float4* p = (const float4*)in;
        float4 v0 = p[i * 2], v1 = p[i * 2 + 1];
        f16x8 o;
        o[0] = (_Float16)v0.x; o[1] = (_Float16)v0.y; o[2] = (_Float16)v0.z; o[3] = (_Float16)v0.w;
        o[4] = (_Float16)v1.x; o[5] = (_Float16)v1.y; o[6] = (_Float16)v1.z; o[7] = (_Float16)v1.w;
        *(f16x8*)(out + (size_t)i * 8) = o;
    }
}

// ---------------------------------------------------------------------------
// fp32 [R][C] -> f16 [C][R]  (tiled 64x64 via LDS)
__global__ __launch_bounds__(256) void transpose_f32_to_f16(
    const float* __restrict__ in, _Float16* __restrict__ out, int R, int C)
{
    __shared__ float tile[64][65];
    int r0 = blockIdx.y * 64, c0 = blockIdx.x * 64;
    int t = threadIdx.x;
#pragma unroll
    for (int p = 0; p < 4; ++p) {
        int lin = p * 256 + t;           // 1024 float4-chunks
        int row = lin >> 4;
        int c4 = (lin & 15) * 4;
        float4 v = *(const float4*)(in + (size_t)(r0 + row) * C + c0 + c4);
        tile[row][c4] = v.x; tile[row][c4 + 1] = v.y;
        tile[row][c4 + 2] = v.z; tile[row][c4 + 3] = v.w;
    }
    __syncthreads();
#pragma unroll
    for (int p = 0; p < 2; ++p) {
        int lin = p * 256 + t;           // 512 f16x8-chunks
        int oc = lin >> 3;
        int ch = (lin & 7) * 8;
        f16x8 o;
#pragma unroll
        for (int e = 0; e < 8; ++e) o[e] = (_Float16)tile[ch + e][oc];
        *(f16x8*)(out + (size_t)(c0 + oc) * R + r0 + ch) = o;
    }
}

// ---------------------------------------------------------------------------
// f16 [R][C] -> f16 [C][R] per head (grid.z = heads)
__global__ __launch_bounds__(256) void transpose_f16(
    const _Float16* __restrict__ in, _Float16* __restrict__ out, int R, int C)
{
    __shared__ _Float16 tile[64][72];
    const _Float16* inh = in + (size_t)blockIdx.z * R * C;
    _Float16* outh = out + (size_t)blockIdx.z * R * C;
    int r0 = blockIdx.y * 64, c0 = blockIdx.x * 64;
    int t = threadIdx.x;
#pragma unroll
    for (int p = 0; p < 2; ++p) {
        int lin = p * 256 + t;
        int row = lin >> 3;
        int ch = (lin & 7) * 8;
        f16x8 v = *(const f16x8*)(inh + (size_t)(r0 + row) * C + c0 + ch);
        *(f16x8*)&tile[row][ch] = v;
    }
    __syncthreads();
#pragma unroll
    for (int p = 0; p < 2; ++p) {
        int lin = p * 256 + t;
        int oc = lin >> 3;
        int ch = (lin & 7) * 8;
        f16x8 o;
#pragma unroll
        for (int e = 0; e < 8; ++e) o[e] = tile[ch + e][oc];
        *(f16x8*)(outh + (size_t)(c0 + oc) * R + r0 + ch) = o;
    }
}

// ---------------------------------------------------------------------------
// f16 MFMA GEMM v2: 2-phase explicit LDS double-buffer (T3-min recipe) + XCD
// chunk swizzle (T1). C[M][Nn] = A[M][K] * Bt[Nn][K]^T + bias.
// 128x128 tile, BK=64, 4 waves (2x2). Per iter: STAGE(next tile, buf^1) is
// issued BEFORE compute(buf); the single __syncthreads (compiler drains
// vmcnt(0)+lgkmcnt(0)) makes the swap race-free.
// EPI=0: fp32 output + bias.  EPI=1: qkv epilogue -> scatter K/Q/V heads (f16).
template <int EPI>
__global__ __launch_bounds__(256) void gemm_f16(
    const _Float16* __restrict__ A, const _Float16* __restrict__ Bt,
    const float* __restrict__ bias, float* __restrict__ Cout,
    _Float16* __restrict__ Kh, _Float16* __restrict__ Qh, _Float16* __restrict__ Vh,
    int M, int Nn, int Kk)
{
    __shared__ _Float16 As[2][128 * 64];   // linear row-major [128][64], 2 bufs
    __shared__ _Float16 Bs[2][128 * 64];   // total 64 KB -> 2 blocks/CU

    // T1: bijective XCD chunking (nwg % 8 == 0 for both call sites).
    // Consecutive in-chunk ids walk bx (n-tiles) first -> A-panel L2 reuse.
    int lin = blockIdx.y * gridDim.x + blockIdx.x;
    int nwg = gridDim.x * gridDim.y;
    int lin2 = (lin & 7) * (nwg >> 3) + (lin >> 3);
    int bx = lin2 % gridDim.x, by = lin2 / gridDim.x;
    int m0 = by * 128, n0 = bx * 128;

    int t = threadIdx.x, lane = t & 63, wid = t >> 6;
    int wr = (wid >> 1) * 64, wc = (wid & 1) * 64;
    int lr = lane & 15, lg = lane >> 4;

    f32x4 acc[4][4] = {};
    int nt = Kk >> 6;

    // prologue: stage tile 0 into buf 0
#pragma unroll
    for (int p = 0; p < 4; ++p) {
        int c = p * 256 + t;
        int row = c >> 3, col = (c & 7) * 8;
        int ubase = (p * 256 + wid * 64) * 8;
        gload_lds16(A  + (size_t)(m0 + row) * Kk + col, &As[0][ubase]);
        gload_lds16(Bt + (size_t)(n0 + row) * Kk + col, &Bs[0][ubase]);
    }
    __syncthreads();

    for (int tt = 0; tt < nt; ++tt) {
        int cur = tt & 1;
        if (tt + 1 < nt) {                 // issue next-tile loads FIRST
            int k0 = (tt + 1) * 64;
#pragma unroll
            for (int p = 0; p < 4; ++p) {
                int c = p * 256 + t;
                int row = c >> 3, col = (c & 7) * 8;
                int ubase = (p * 256 + wid * 64) * 8;
                gload_lds16(A  + (size_t)(m0 + row) * Kk + k0 + col, &As[cur ^ 1][ubase]);
                gload_lds16(Bt + (size_t)(n0 + row) * Kk + k0 + col, &Bs[cur ^ 1][ubase]);
            }
        }
        const _Float16* Ac = &As[cur][0];
        const _Float16* Bc = &Bs[cur][0];
#pragma unroll
        for (int kk = 0; kk < 2; ++kk) {
            f16x8 af[4], bfr[4];
#pragma unroll
            for (int i = 0; i < 4; ++i) {
                af[i]  = *(const f16x8*)&Ac[(wr + i * 16 + lr) * 64 + kk * 32 + lg * 8];
                bfr[i] = *(const f16x8*)&Bc[(wc + i * 16 + lr) * 64 + kk * 32 + lg * 8];
            }
#pragma unroll
            for (int i = 0; i < 4; ++i)
#pragma unroll
                for (int jn = 0; jn < 4; ++jn)
                    acc[i][jn] = __builtin_amdgcn_mfma_f32_16x16x32_f16(
                        af[i], bfr[jn], acc[i][jn], 0, 0, 0);
        }
        __syncthreads();   // drains vmcnt(0)+lgkmcnt(0): prefetch landed, reads done
    }

    // epilogue: C/D layout col = lane&15, row = (lane>>4)*4 + j  [m89-verified]
#pragma unroll
    for (int i = 0; i < 4; ++i)
#pragma unroll
        for (int jn = 0; jn < 4; ++jn) {
            int gc = n0 + wc + jn * 16 + lr;
            float bv = bias[gc];
#pragma unroll
            for (int j = 0; j < 4; ++j) {
                int gr = m0 + wr + i * 16 + lg * 4 + j;
                float v = acc[i][jn][j] + bv;
                if constexpr (EPI == 0) {
                    Cout[(size_t)gr * Nn + gc] = v;
                } else {
                    int sec = gc >> 10, idx = gc & 1023;
                    int h = idx >> 6, d = idx & 63;
                    int bb = gr >> 10, pos = gr & 1023;
                    size_t hoff = (((size_t)(bb * 16 + h) * 1024) + pos) * 64 + d;
                    if (sec == 0)      Kh[hoff] = (_Float16)v;
                    else if (sec == 1) Qh[hoff] = (_Float16)(v * (0.125f * LOG2E));
                    else               Vh[hoff] = (_Float16)v;
                }
            }
        }
}

// ---------------------------------------------------------------------------
// Flash attention v3: swapped QK^T + cooperative double-buffered K/V LDS
// staging (pre-swizzled gload_lds source, XOR ((row&7)<<4) on read) + XCD
// bh-chunk swizzle. grid = 1024 blocks (flat), 4 waves x 16 q-rows, KVBLK=64.
// Q pre-scaled by 0.125*log2(e); softmax in exp2 domain.
// Qh/Kh: [bh][n][64], Vt: [bh][64][n], attO: [B*N][H*64]
__global__ __launch_bounds__(256) void attn_kernel(
    const _Float16* __restrict__ Qh, const _Float16* __restrict__ Kh,
    const _Float16* __restrict__ Vt, _Float16* __restrict__ attO)
{
    __shared__ _Float16 Ks[2][64 * 64];   // [k-row][d], XOR-swizzled cols, 8KB/buf
    __shared__ _Float16 Vs[2][64 * 64];   // [d-row][k], XOR-swizzled cols
    __shared__ _Float16 Pl[4][16 * 64];   // per-wave P[q][k], XOR-swizzled cols

    // XCD swizzle: consecutive dispatch ids round-robin XCDs; give each XCD
    // 8 complete bh's (16 q-blocks each) so K/V stay in its L2.
    int wg = blockIdx.x;                        // 0..1023, 1024 % 8 == 0
    int swz = (wg & 7) * 128 + (wg >> 3);
    int bh = swz >> 4, qt = swz & 15;
    int b = bh >> 4, h = bh & 15;

    int tid = threadIdx.x;
    int wid = tid >> 6, lane = tid & 63;
    int lr = lane & 15, lg = lane >> 4;
    int q0 = qt * 64 + wid * 16;
    const _Float16* Qb = Qh + (size_t)bh * (1024 * 64);
    const _Float16* Kb = Kh + (size_t)bh * (1024 * 64);
    const _Float16* Vb = Vt + (size_t)bh * (64 * 1024);

    // staging geometry: 512 16B-chunks per tile, 2 instrs/thread.
    // chunk c -> row r = c>>3, lds byte col (c&7)*16; source byte col is
    // pre-swizzled so LDS stays linear: sc = ((c&7)*16) ^ ((r&7)<<4).
    int c0 = tid, c1 = 256 + tid;
    int r0 = c0 >> 3, sc0 = ((c0 & 7) * 16) ^ ((r0 & 7) << 4);
    int r1 = c1 >> 3, sc1 = ((c1 & 7) * 16) ^ ((r1 & 7) << 4);
    int ub0 = (wid * 64) * 8, ub1 = (256 + wid * 64) * 8;  // wave-uniform LDS bases

    // Q as B-operand of QK^T: col = q = lr, contraction d = lg*8+e
    f16x8 qf0 = *(const f16x8*)(Qb + (size_t)(q0 + lr) * 64 + lg * 8);
    f16x8 qf1 = *(const f16x8*)(Qb + (size_t)(q0 + lr) * 64 + 32 + lg * 8);

    float m = -1e30f, l = 0.f;
    f32x4 o[4] = {};   // O^T[d][q]: d = db*16 + lg*4 + j, q = lr
    int xr = (lr & 7) << 4;

    // prologue: stage tile 0
    gload_lds16(Kb + (size_t)r0 * 64 + (sc0 >> 1), &Ks[0][ub0]);
    gload_lds16(Kb + (size_t)r1 * 64 + (sc1 >> 1), &Ks[0][ub1]);
    gload_lds16(Vb + (size_t)r0 * 1024 + (sc0 >> 1), &Vs[0][ub0]);
    gload_lds16(Vb + (size_t)r1 * 1024 + (sc1 >> 1), &Vs[0][ub1]);
    __syncthreads();

    for (int t = 0; t < 16; ++t) {
        int cur = t & 1;
        if (t < 15) {                       // async prefetch of next tile
            int kn = (t + 1) * 64;
            gload_lds16(Kb + (size_t)(kn + r0) * 64 + (sc0 >> 1), &Ks[cur ^ 1][ub0]);
            gload_lds16(Kb + (size_t)(kn + r1) * 64 + (sc1 >> 1), &Ks[cur ^ 1][ub1]);
            gload_lds16(Vb + (size_t)r0 * 1024 + kn + (sc0 >> 1), &Vs[cur ^ 1][ub0]);
            gload_lds16(Vb + (size_t)r1 * 1024 + kn + (sc1 >> 1), &Vs[cur ^ 1][ub1]);
        }
        const _Float16* Kc = &Ks[cur][0];
        const _Float16* Vc = &Vs[cur][0];

        // S[k][q] = mfma(A = K rows, B = Q^T): s[kb][j] at k=kb*16+lg*4+j, q=lr
        f32x4 s[4] = {};
#pragma unroll
        for (int kb = 0; kb < 4; ++kb) {
            const char* krow = (const char*)(Kc + (kb * 16 + lr) * 64);
            f16x8 kf0 = *(const f16x8*)(krow + ((lg * 16) ^ xr));
            f16x8 kf1 = *(const f16x8*)(krow + ((64 + lg * 16) ^ xr));
            s[kb] = __builtin_amdgcn_mfma_f32_16x16x32_f16(kf0, qf0, s[kb], 0, 0, 0);
            s[kb] = __builtin_amdgcn_mfma_f32_16x16x32_f16(kf1, qf1, s[kb], 0, 0, 0);
        }
        // online softmax: 16 values in-lane, k split across lane-groups only
        float a0 = fmaxf(fmaxf(s[0][0], s[0][1]), fmaxf(s[0][2], s[0][3]));
        float a1 = fmaxf(fmaxf(s[1][0], s[1][1]), fmaxf(s[1][2], s[1][3]));
        float a2 = fmaxf(fmaxf(s[2][0], s[2][1]), fmaxf(s[2][2], s[2][3]));
        float a3 = fmaxf(fmaxf(s[3][0], s[3][1]), fmaxf(s[3][2], s[3][3]));
        float pmax = fmaxf(fmaxf(a0, a1), fmaxf(a2, a3));
        pmax = fmaxf(pmax, __shfl_xor(pmax, 16));
        pmax = fmaxf(pmax, __shfl_xor(pmax, 32));
        float mnew = fmaxf(m, pmax);
        float corr = exp2f(m - mnew);
#pragma unroll
        for (int kb = 0; kb < 4; ++kb)
#pragma unroll
            for (int j = 0; j < 4; ++j)
                s[kb][j] = exp2f(s[kb][j] - mnew);
        float rr0 = (s[0][0] + s[0][1]) + (s[0][2] + s[0][3]);
        float rr1 = (s[1][0] + s[1][1]) + (s[1][2] + s[1][3]);
        float rr2 = (s[2][0] + s[2][1]) + (s[2][2] + s[2][3]);
        float rr3 = (s[3][0] + s[3][1]) + (s[3][2] + s[3][3]);
        float rs = (rr0 + rr1) + (rr2 + rr3);
        rs += __shfl_xor(rs, 16);
        rs += __shfl_xor(rs, 32);
        l = l * corr + rs;
        m = mnew;
#pragma unroll
        for (int db = 0; db < 4; ++db)
#pragma unroll
            for (int j = 0; j < 4; ++j) o[db][j] *= corr;

        // P -> LDS (XOR-swizzled) -> PV B-fragments
        char* prow = (char*)&Pl[wid][lr * 64];
#pragma unroll
        for (int kb = 0; kb < 4; ++kb) {
            f16x4 w;
#pragma unroll
            for (int j = 0; j < 4; ++j) w[j] = (_Float16)s[kb][j];
            *(f16x4*)(prow + ((kb * 32 + lg * 8) ^ xr)) = w;
        }
        f16x8 pf0 = *(const f16x8*)(prow + ((lg * 16) ^ xr));
        f16x8 pf1 = *(const f16x8*)(prow + ((64 + lg * 16) ^ xr));

        // O^T[d][q] += mfma(A = V rows (d), B = P[k][q])
#pragma unroll
        for (int db = 0; db < 4; ++db) {
            const char* vrow = (const char*)(Vc + (db * 16 + lr) * 64);
            f16x8 vf0 = *(const f16x8*)(vrow + ((lg * 16) ^ xr));
            f16x8 vf1 = *(const f16x8*)(vrow + ((64 + lg * 16) ^ xr));
            o[db] = __builtin_amdgcn_mfma_f32_16x16x32_f16(vf0, pf0, o[db], 0, 0, 0);
            o[db] = __builtin_amdgcn_mfma_f32_16x16x32_f16(vf1, pf1, o[db], 0, 0, 0);
        }
        __syncthreads();   // drains vmcnt (prefetch landed) + all reads of cur done
    }

    float li = 1.f / l;
#pragma unroll
    for (int db = 0; db < 4; ++db) {
        f16x4 w;
#pragma unroll
        for (int j = 0; j < 4; ++j) w[j] = (_Float16)(o[db][j] * li);
        *(f16x4*)(attO + ((size_t)b * 1024 + q0 + lr) * 1024 + h * 64 + db * 16 + lg * 4) = w;
    }
}

// ---------------------------------------------------------------------------
extern "C" void kernel_launch(void* const* d_in, const int* in_sizes, int n_in,
                              void* d_out, int out_size, void* d_ws, size_t ws_size,
                              hipStream_t stream)
{
    const float* x    = (const float*)d_in[0];   // [4096][1024]
    const float* Wqkv = (const float*)d_in[1];   // [1024][3072]
    const float* bqkv = (const float*)d_in[2];   // [3072]
    const float* Wout = (const float*)d_in[3];   // [1024][1024]
    const float* bout = (const float*)d_in[4];   // [1024]
    float* out = (float*)d_out;                  // [4096][1024]

    char* ws = (char*)d_ws;
    _Float16* xb    = (_Float16*)(ws);                       // 8 MB  [4096][1024]
    _Float16* Vt    = (_Float16*)(ws);                       // aliases xb (xb dead after qkv GEMM)
    _Float16* Wqkvt = (_Float16*)(ws + ((size_t)8  << 20));  // 6 MB  [3072][1024]
    _Float16* Woutt = (_Float16*)(ws + ((size_t)14 << 20));  // 2 MB  [1024][1024]
    _Float16* Qh    = (_Float16*)(ws + ((size_t)16 << 20));  // 8 MB  [64][1024][64]
    _Float16* Kh    = (_Float16*)(ws + ((size_t)24 << 20));  // 8 MB
    _Float16* Vh    = (_Float16*)(ws + ((size_t)32 << 20));  // 8 MB
    _Float16* attO  = (_Float16*)(ws + ((size_t)40 << 20));  // 8 MB  [4096][1024]
    // total 48 MB

    // 1. convert / transpose weights & activations to f16
    cvt_f32_f16<<<2048, 256, 0, stream>>>(x, xb, 4096 * 1024 / 8);
    transpose_f32_to_f16<<<dim3(48, 16), 256, 0, stream>>>(Wqkv, Wqkvt, 1024, 3072);
    transpose_f32_to_f16<<<dim3(16, 16), 256, 0, stream>>>(Wout, Woutt, 1024, 1024);

    // 2. qkv GEMM with K/Q/V head-scatter epilogue
    gemm_f16<1><<<dim3(24, 32), 256, 0, stream>>>(
        xb, Wqkvt, bqkv, nullptr, Kh, Qh, Vh, 4096, 3072, 1024);

    // 3. V -> V^T per head (writes Vt over the now-dead xb region)
    transpose_f16<<<dim3(1, 16, 64), 256, 0, stream>>>(Vh, Vt, 1024, 64);

    // 4. flash attention
    attn_kernel<<<1024, 256, 0, stream>>>(Qh, Kh, Vt, attO);

    // 5. output projection
    gemm_f16<0><<<dim3(8, 32), 256, 0, stream>>>(
        attO, Woutt, bout, out, nullptr, nullptr, nullptr, 4096, 1024, 1024);
}

// Round 7
// 190.939 us; speedup vs baseline: 1.1067x; 1.1067x over previous
//
#include <hip/hip_runtime.h>
#include <hip/hip_bf16.h>
#include <cstddef>
#include <cmath>

// Problem constants: B=4, N=1024, H=16, hd=64, EMB=1024, M=B*N=4096
// split order in reference: K, Q, V (cols 0..1023 = K, 1024..2047 = Q, 2048.. = V)

typedef _Float16 f16x4 __attribute__((ext_vector_type(4)));
typedef _Float16 f16x8 __attribute__((ext_vector_type(8)));
typedef float    f32x4 __attribute__((ext_vector_type(4)));

#define LOG2E 1.4426950408889634f

// async global->LDS, 16B per lane. LDS dest: wave-uniform base + lane*16.
__device__ __forceinline__ void gload_lds16(const void* g, void* l) {
    __builtin_amdgcn_global_load_lds(
        (const __attribute__((address_space(1))) unsigned int*)g,
        (__attribute__((address_space(3))) unsigned int*)l, 16, 0, 0);
}

// ---------------------------------------------------------------------------
// fp32 -> f16 elementwise convert (vectorized 8/thread)
__global__ __launch_bounds__(256) void cvt_f32_f16(
    const float* __restrict__ in, _Float16* __restrict__ out, int n8)
{
    int i = blockIdx.x * 256 + threadIdx.x;
    if (i < n8) {
        const float4* p = (const float4*)in;
        float4 v0 = p[i * 2], v1 = p[i * 2 + 1];
        f16x8 o;
        o[0] = (_Float16)v0.x; o[1] = (_Float16)v0.y; o[2] = (_Float16)v0.z; o[3] = (_Float16)v0.w;
        o[4] = (_Float16)v1.x; o[5] = (_Float16)v1.y; o[6] = (_Float16)v1.z; o[7] = (_Float16)v1.w;
        *(f16x8*)(out + (size_t)i * 8) = o;
    }
}

// ---------------------------------------------------------------------------
// fp32 [R][C] -> f16 [C][R]  (tiled 64x64 via LDS)
__global__ __launch_bounds__(256) void transpose_f32_to_f16(
    const float* __restrict__ in, _Float16* __restrict__ out, int R, int C)
{
    __shared__ float tile[64][65];
    int r0 = blockIdx.y * 64, c0 = blockIdx.x * 64;
    int t = threadIdx.x;
#pragma unroll
    for (int p = 0; p < 4; ++p) {
        int lin = p * 256 + t;           // 1024 float4-chunks
        int row = lin >> 4;
        int c4 = (lin & 15) * 4;
        float4 v = *(const float4*)(in + (size_t)(r0 + row) * C + c0 + c4);
        tile[row][c4] = v.x; tile[row][c4 + 1] = v.y;
        tile[row][c4 + 2] = v.z; tile[row][c4 + 3] = v.w;
    }
    __syncthreads();
#pragma unroll
    for (int p = 0; p < 2; ++p) {
        int lin = p * 256 + t;           // 512 f16x8-chunks
        int oc = lin >> 3;
        int ch = (lin & 7) * 8;
        f16x8 o;
#pragma unroll
        for (int e = 0; e < 8; ++e) o[e] = (_Float16)tile[ch + e][oc];
        *(f16x8*)(out + (size_t)(c0 + oc) * R + r0 + ch) = o;
    }
}

// ---------------------------------------------------------------------------
// f16 [R][C] -> f16 [C][R] per head (grid.z = heads)
__global__ __launch_bounds__(256) void transpose_f16(
    const _Float16* __restrict__ in, _Float16* __restrict__ out, int R, int C)
{
    __shared__ _Float16 tile[64][72];
    const _Float16* inh = in + (size_t)blockIdx.z * R * C;
    _Float16* outh = out + (size_t)blockIdx.z * R * C;
    int r0 = blockIdx.y * 64, c0 = blockIdx.x * 64;
    int t = threadIdx.x;
#pragma unroll
    for (int p = 0; p < 2; ++p) {
        int lin = p * 256 + t;
        int row = lin >> 3;
        int ch = (lin & 7) * 8;
        f16x8 v = *(const f16x8*)(inh + (size_t)(r0 + row) * C + c0 + ch);
        *(f16x8*)&tile[row][ch] = v;
    }
    __syncthreads();
#pragma unroll
    for (int p = 0; p < 2; ++p) {
        int lin = p * 256 + t;
        int oc = lin >> 3;
        int ch = (lin & 7) * 8;
        f16x8 o;
#pragma unroll
        for (int e = 0; e < 8; ++e) o[e] = tile[ch + e][oc];
        *(f16x8*)(outh + (size_t)(c0 + oc) * R + r0 + ch) = o;
    }
}

// ---------------------------------------------------------------------------
// gemm256: 256x256 tile, BK=32, 3-stage LDS pipeline with COUNTED vmcnt
// (T3+T4), T2 XOR-swizzle, T5 setprio, T1 XCD chunking. 512 thr = 8 waves
// (2M x 4N), per-wave output 128x64 (acc[8][4] f32x4).
// Pipeline: iter i computes buf i%3; stages iter i+2 into buf (i+2)%3.
// Iter top: vmcnt(4) (keep newest 4 loads in flight - NEVER 0) + raw barrier.
// Tail stages clamp to k=0 (garbage staged into a never-read buf) so the
// vmcnt count stays exact through the last iteration.
// EPI=0: fp32 out + bias.  EPI=1: qkv scatter epilogue.
template <int EPI>
__global__ __launch_bounds__(512, 2) void gemm256(
    const _Float16* __restrict__ A, const _Float16* __restrict__ Bt,
    const float* __restrict__ bias, float* __restrict__ Cout,
    _Float16* __restrict__ Kh, _Float16* __restrict__ Qh, _Float16* __restrict__ Vh,
    int M, int Nn, int Kk)
{
    __shared__ _Float16 As[3][256 * 32];   // 48 KB
    __shared__ _Float16 Bs[3][256 * 32];   // 48 KB

    // T1: bijective XCD chunking (192 % 8 == 0)
    int lin = blockIdx.y * gridDim.x + blockIdx.x;
    int nwg = gridDim.x * gridDim.y;
    int lin2 = (lin & 7) * (nwg >> 3) + (lin >> 3);
    int bx = lin2 % gridDim.x, by = lin2 / gridDim.x;
    int m0 = by * 256, n0 = bx * 256;

    int tid = threadIdx.x, lane = tid & 63, wid = tid >> 6;
    int wm = wid >> 2, wn = wid & 3;          // 2M x 4N wave grid
    int lr = lane & 15, lg = lane >> 4;

    // staging: per thread, 4 gload_lds per iter (A rows r0/r1, B rows r0/r1).
    // chunk: row = srow (+128), col elems (tid&3)*8; source col pre-swizzled
    // with ((row&6)<<2) (elem) so LDS stays linear (rule #21).
    int srow = tid >> 2;
    int scol = ((tid & 3) * 8) ^ ((srow & 6) << 2);   // (128+srow)&6 == srow&6
    const _Float16* pa0 = A  + (size_t)(m0 + srow) * Kk + scol;
    const _Float16* pa1 = A  + (size_t)(m0 + 128 + srow) * Kk + scol;
    const _Float16* pb0 = Bt + (size_t)(n0 + srow) * Kk + scol;
    const _Float16* pb1 = Bt + (size_t)(n0 + 128 + srow) * Kk + scol;
    int d0 = (wid * 64) * 8;            // wave-uniform LDS elem bases
    int d1 = (512 + wid * 64) * 8;

    f32x4 acc[8][4] = {};               // [mh*4+mf][nf]
    const int NIT = Kk >> 5;            // K-tiles of 32

    // prologue: stage iters 0 and 1
    {
        gload_lds16(pa0, &As[0][d0]); gload_lds16(pa1, &As[0][d1]);
        gload_lds16(pb0, &Bs[0][d0]); gload_lds16(pb1, &Bs[0][d1]);
        gload_lds16(pa0 + 32, &As[1][d0]); gload_lds16(pa1 + 32, &As[1][d1]);
        gload_lds16(pb0 + 32, &Bs[1][d0]); gload_lds16(pb1 + 32, &Bs[1][d1]);
    }

    for (int i = 0; i < NIT; ++i) {
        const _Float16* Ab = &As[i % 3][0];
        const _Float16* Bb = &Bs[i % 3][0];
        int sb = (i + 2) % 3;
        int ks = (i + 2 < NIT) ? (i + 2) * 32 : 0;   // tail clamp keeps count

        // counted wait: all but the newest 4 loads done => THIS iter's landed
        asm volatile("s_waitcnt vmcnt(4)" ::: "memory");
        __builtin_amdgcn_s_barrier();    // publish cross-wave (no drain)

        // ---- phase 1: ds-read B all-nf + A mh0; stage; 16 MFMA ----
        f16x8 bf[4], af[4];
#pragma unroll
        for (int nf = 0; nf < 4; ++nf) {
            int rn = wn * 64 + nf * 16 + lr;
            bf[nf] = *(const f16x8*)&Bb[rn * 32 + ((lg * 8) ^ ((rn & 6) << 2))];
        }
#pragma unroll
        for (int mf = 0; mf < 4; ++mf) {
            int ra = wm * 128 + mf * 16 + lr;
            af[mf] = *(const f16x8*)&Ab[ra * 32 + ((lg * 8) ^ ((ra & 6) << 2))];
        }
        gload_lds16(pa0 + ks, &As[sb][d0]);
        gload_lds16(pa1 + ks, &As[sb][d1]);
        asm volatile("s_waitcnt lgkmcnt(0)" ::: "memory");
        __builtin_amdgcn_sched_barrier(0);
        __builtin_amdgcn_s_setprio(1);
#pragma unroll
        for (int mf = 0; mf < 4; ++mf)
#pragma unroll
            for (int nf = 0; nf < 4; ++nf)
                acc[mf][nf] = __builtin_amdgcn_mfma_f32_16x16x32_f16(
                    af[mf], bf[nf], acc[mf][nf], 0, 0, 0);
        __builtin_amdgcn_s_setprio(0);

        // ---- phase 2: ds-read A mh1; stage; 16 MFMA ----
#pragma unroll
        for (int mf = 0; mf < 4; ++mf) {
            int ra = wm * 128 + 64 + mf * 16 + lr;
            af[mf] = *(const f16x8*)&Ab[ra * 32 + ((lg * 8) ^ ((ra & 6) << 2))];
        }
        gload_lds16(pb0 + ks, &Bs[sb][d0]);
        gload_lds16(pb1 + ks, &Bs[sb][d1]);
        asm volatile("s_waitcnt lgkmcnt(0)" ::: "memory");
        __builtin_amdgcn_sched_barrier(0);
        __builtin_amdgcn_s_setprio(1);
#pragma unroll
        for (int mf = 0; mf < 4; ++mf)
#pragma unroll
            for (int nf = 0; nf < 4; ++nf)
                acc[4 + mf][nf] = __builtin_amdgcn_mfma_f32_16x16x32_f16(
                    af[mf], bf[nf], acc[4 + mf][nf], 0, 0, 0);
        __builtin_amdgcn_s_setprio(0);
    }

    // epilogue: C/D frag layout col = lane&15, row = (lane>>4)*4 + j
#pragma unroll
    for (int mh = 0; mh < 2; ++mh)
#pragma unroll
        for (int mf = 0; mf < 4; ++mf)
#pragma unroll
            for (int nf = 0; nf < 4; ++nf) {
                int gc = n0 + wn * 64 + nf * 16 + lr;
                float bv = bias[gc];
#pragma unroll
                for (int j = 0; j < 4; ++j) {
                    int gr = m0 + wm * 128 + mh * 64 + mf * 16 + lg * 4 + j;
                    float v = acc[mh * 4 + mf][nf][j] + bv;
                    if constexpr (EPI == 0) {
                        Cout[(size_t)gr * Nn + gc] = v;
                    } else {
                        int sec = gc >> 10, idx = gc & 1023;
                        int h = idx >> 6, d = idx & 63;
                        int bb = gr >> 10, pos = gr & 1023;
                        size_t hoff = (((size_t)(bb * 16 + h) * 1024) + pos) * 64 + d;
                        if (sec == 0)      Kh[hoff] = (_Float16)v;
                        else if (sec == 1) Qh[hoff] = (_Float16)(v * (0.125f * LOG2E));
                        else               Vh[hoff] = (_Float16)v;
                    }
                }
            }
}

// ---------------------------------------------------------------------------
// f16 MFMA GEMM (2-phase dbuf, validated) — used for the output projection.
template <int EPI>
__global__ __launch_bounds__(256) void gemm_f16(
    const _Float16* __restrict__ A, const _Float16* __restrict__ Bt,
    const float* __restrict__ bias, float* __restrict__ Cout,
    _Float16* __restrict__ Kh, _Float16* __restrict__ Qh, _Float16* __restrict__ Vh,
    int M, int Nn, int Kk)
{
    __shared__ _Float16 As[2][128 * 64];
    __shared__ _Float16 Bs[2][128 * 64];

    int lin = blockIdx.y * gridDim.x + blockIdx.x;
    int nwg = gridDim.x * gridDim.y;
    int lin2 = (lin & 7) * (nwg >> 3) + (lin >> 3);
    int bx = lin2 % gridDim.x, by = lin2 / gridDim.x;
    int m0 = by * 128, n0 = bx * 128;

    int t = threadIdx.x, lane = t & 63, wid = t >> 6;
    int wr = (wid >> 1) * 64, wc = (wid & 1) * 64;
    int lr = lane & 15, lg = lane >> 4;

    f32x4 acc[4][4] = {};
    int nt = Kk >> 6;

#pragma unroll
    for (int p = 0; p < 4; ++p) {
        int c = p * 256 + t;
        int row = c >> 3, col = (c & 7) * 8;
        int ubase = (p * 256 + wid * 64) * 8;
        gload_lds16(A  + (size_t)(m0 + row) * Kk + col, &As[0][ubase]);
        gload_lds16(Bt + (size_t)(n0 + row) * Kk + col, &Bs[0][ubase]);
    }
    __syncthreads();

    for (int tt = 0; tt < nt; ++tt) {
        int cur = tt & 1;
        if (tt + 1 < nt) {
            int k0 = (tt + 1) * 64;
#pragma unroll
            for (int p = 0; p < 4; ++p) {
                int c = p * 256 + t;
                int row = c >> 3, col = (c & 7) * 8;
                int ubase = (p * 256 + wid * 64) * 8;
                gload_lds16(A  + (size_t)(m0 + row) * Kk + k0 + col, &As[cur ^ 1][ubase]);
                gload_lds16(Bt + (size_t)(n0 + row) * Kk + k0 + col, &Bs[cur ^ 1][ubase]);
            }
        }
        const _Float16* Ac = &As[cur][0];
        const _Float16* Bc = &Bs[cur][0];
#pragma unroll
        for (int kk = 0; kk < 2; ++kk) {
            f16x8 af[4], bfr[4];
#pragma unroll
            for (int i = 0; i < 4; ++i) {
                af[i]  = *(const f16x8*)&Ac[(wr + i * 16 + lr) * 64 + kk * 32 + lg * 8];
                bfr[i] = *(const f16x8*)&Bc[(wc + i * 16 + lr) * 64 + kk * 32 + lg * 8];
            }
#pragma unroll
            for (int i = 0; i < 4; ++i)
#pragma unroll
                for (int jn = 0; jn < 4; ++jn)
                    acc[i][jn] = __builtin_amdgcn_mfma_f32_16x16x32_f16(
                        af[i], bfr[jn], acc[i][jn], 0, 0, 0);
        }
        __syncthreads();
    }

#pragma unroll
    for (int i = 0; i < 4; ++i)
#pragma unroll
        for (int jn = 0; jn < 4; ++jn) {
            int gc = n0 + wc + jn * 16 + lr;
            float bv = bias[gc];
#pragma unroll
            for (int j = 0; j < 4; ++j) {
                int gr = m0 + wr + i * 16 + lg * 4 + j;
                float v = acc[i][jn][j] + bv;
                if constexpr (EPI == 0) {
                    Cout[(size_t)gr * Nn + gc] = v;
                } else {
                    int sec = gc >> 10, idx = gc & 1023;
                    int h = idx >> 6, d = idx & 63;
                    int bb = gr >> 10, pos = gr & 1023;
                    size_t hoff = (((size_t)(bb * 16 + h) * 1024) + pos) * 64 + d;
                    if (sec == 0)      Kh[hoff] = (_Float16)v;
                    else if (sec == 1) Qh[hoff] = (_Float16)(v * (0.125f * LOG2E));
                    else               Vh[hoff] = (_Float16)v;
                }
            }
        }
}

// ---------------------------------------------------------------------------
// Flash attention v3 (validated): swapped QK^T + dbuf K/V LDS staging
// (pre-swizzled gload source + XOR read) + XCD bh-chunk swizzle.
__global__ __launch_bounds__(256) void attn_kernel(
    const _Float16* __restrict__ Qh, const _Float16* __restrict__ Kh,
    const _Float16* __restrict__ Vt, _Float16* __restrict__ attO)
{
    __shared__ _Float16 Ks[2][64 * 64];
    __shared__ _Float16 Vs[2][64 * 64];
    __shared__ _Float16 Pl[4][16 * 64];

    int wg = blockIdx.x;
    int swz = (wg & 7) * 128 + (wg >> 3);
    int bh = swz >> 4, qt = swz & 15;
    int b = bh >> 4, h = bh & 15;

    int tid = threadIdx.x;
    int wid = tid >> 6, lane = tid & 63;
    int lr = lane & 15, lg = lane >> 4;
    int q0 = qt * 64 + wid * 16;
    const _Float16* Qb = Qh + (size_t)bh * (1024 * 64);
    const _Float16* Kb = Kh + (size_t)bh * (1024 * 64);
    const _Float16* Vb = Vt + (size_t)bh * (64 * 1024);

    int c0 = tid, c1 = 256 + tid;
    int r0 = c0 >> 3, sc0 = ((c0 & 7) * 16) ^ ((r0 & 7) << 4);
    int r1 = c1 >> 3, sc1 = ((c1 & 7) * 16) ^ ((r1 & 7) << 4);
    int ub0 = (wid * 64) * 8, ub1 = (256 + wid * 64) * 8;

    f16x8 qf0 = *(const f16x8*)(Qb + (size_t)(q0 + lr) * 64 + lg * 8);
    f16x8 qf1 = *(const f16x8*)(Qb + (size_t)(q0 + lr) * 64 + 32 + lg * 8);

    float m = -1e30f, l = 0.f;
    f32x4 o[4] = {};
    int xr = (lr & 7) << 4;

    gload_lds16(Kb + (size_t)r0 * 64 + (sc0 >> 1), &Ks[0][ub0]);
    gload_lds16(Kb + (size_t)r1 * 64 + (sc1 >> 1), &Ks[0][ub1]);
    gload_lds16(Vb + (size_t)r0 * 1024 + (sc0 >> 1), &Vs[0][ub0]);
    gload_lds16(Vb + (size_t)r1 * 1024 + (sc1 >> 1), &Vs[0][ub1]);
    __syncthreads();

    for (int t = 0; t < 16; ++t) {
        int cur = t & 1;
        if (t < 15) {
            int kn = (t + 1) * 64;
            gload_lds16(Kb + (size_t)(kn + r0) * 64 + (sc0 >> 1), &Ks[cur ^ 1][ub0]);
            gload_lds16(Kb + (size_t)(kn + r1) * 64 + (sc1 >> 1), &Ks[cur ^ 1][ub1]);
            gload_lds16(Vb + (size_t)r0 * 1024 + kn + (sc0 >> 1), &Vs[cur ^ 1][ub0]);
            gload_lds16(Vb + (size_t)r1 * 1024 + kn + (sc1 >> 1), &Vs[cur ^ 1][ub1]);
        }
        const _Float16* Kc = &Ks[cur][0];
        const _Float16* Vc = &Vs[cur][0];

        f32x4 s[4] = {};
#pragma unroll
        for (int kb = 0; kb < 4; ++kb) {
            const char* krow = (const char*)(Kc + (kb * 16 + lr) * 64);
            f16x8 kf0 = *(const f16x8*)(krow + ((lg * 16) ^ xr));
            f16x8 kf1 = *(const f16x8*)(krow + ((64 + lg * 16) ^ xr));
            s[kb] = __builtin_amdgcn_mfma_f32_16x16x32_f16(kf0, qf0, s[kb], 0, 0, 0);
            s[kb] = __builtin_amdgcn_mfma_f32_16x16x32_f16(kf1, qf1, s[kb], 0, 0, 0);
        }
        float a0 = fmaxf(fmaxf(s[0][0], s[0][1]), fmaxf(s[0][2], s[0][3]));
        float a1 = fmaxf(fmaxf(s[1][0], s[1][1]), fmaxf(s[1][2], s[1][3]));
        float a2 = fmaxf(fmaxf(s[2][0], s[2][1]), fmaxf(s[2][2], s[2][3]));
        float a3 = fmaxf(fmaxf(s[3][0], s[3][1]), fmaxf(s[3][2], s[3][3]));
        float pmax = fmaxf(fmaxf(a0, a1), fmaxf(a2, a3));
        pmax = fmaxf(pmax, __shfl_xor(pmax, 16));
        pmax = fmaxf(pmax, __shfl_xor(pmax, 32));
        float mnew = fmaxf(m, pmax);
        float corr = exp2f(m - mnew);
#pragma unroll
        for (int kb = 0; kb < 4; ++kb)
#pragma unroll
            for (int j = 0; j < 4; ++j)
                s[kb][j] = exp2f(s[kb][j] - mnew);
        float rr0 = (s[0][0] + s[0][1]) + (s[0][2] + s[0][3]);
        float rr1 = (s[1][0] + s[1][1]) + (s[1][2] + s[1][3]);
        float rr2 = (s[2][0] + s[2][1]) + (s[2][2] + s[2][3]);
        float rr3 = (s[3][0] + s[3][1]) + (s[3][2] + s[3][3]);
        float rs = (rr0 + rr1) + (rr2 + rr3);
        rs += __shfl_xor(rs, 16);
        rs += __shfl_xor(rs, 32);
        l = l * corr + rs;
        m = mnew;
#pragma unroll
        for (int db = 0; db < 4; ++db)
#pragma unroll
            for (int j = 0; j < 4; ++j) o[db][j] *= corr;

        char* prow = (char*)&Pl[wid][lr * 64];
#pragma unroll
        for (int kb = 0; kb < 4; ++kb) {
            f16x4 w;
#pragma unroll
            for (int j = 0; j < 4; ++j) w[j] = (_Float16)s[kb][j];
            *(f16x4*)(prow + ((kb * 32 + lg * 8) ^ xr)) = w;
        }
        f16x8 pf0 = *(const f16x8*)(prow + ((lg * 16) ^ xr));
        f16x8 pf1 = *(const f16x8*)(prow + ((64 + lg * 16) ^ xr));

#pragma unroll
        for (int db = 0; db < 4; ++db) {
            const char* vrow = (const char*)(Vc + (db * 16 + lr) * 64);
            f16x8 vf0 = *(const f16x8*)(vrow + ((lg * 16) ^ xr));
            f16x8 vf1 = *(const f16x8*)(vrow + ((64 + lg * 16) ^ xr));
            o[db] = __builtin_amdgcn_mfma_f32_16x16x32_f16(vf0, pf0, o[db], 0, 0, 0);
            o[db] = __builtin_amdgcn_mfma_f32_16x16x32_f16(vf1, pf1, o[db], 0, 0, 0);
        }
        __syncthreads();
    }

    float li = 1.f / l;
#pragma unroll
    for (int db = 0; db < 4; ++db) {
        f16x4 w;
#pragma unroll
        for (int j = 0; j < 4; ++j) w[j] = (_Float16)(o[db][j] * li);
        *(f16x4*)(attO + ((size_t)b * 1024 + q0 + lr) * 1024 + h * 64 + db * 16 + lg * 4) = w;
    }
}

// ---------------------------------------------------------------------------
extern "C" void kernel_launch(void* const* d_in, const int* in_sizes, int n_in,
                              void* d_out, int out_size, void* d_ws, size_t ws_size,
                              hipStream_t stream)
{
    const float* x    = (const float*)d_in[0];   // [4096][1024]
    const float* Wqkv = (const float*)d_in[1];   // [1024][3072]
    const float* bqkv = (const float*)d_in[2];   // [3072]
    const float* Wout = (const float*)d_in[3];   // [1024][1024]
    const float* bout = (const float*)d_in[4];   // [1024]
    float* out = (float*)d_out;                  // [4096][1024]

    char* ws = (char*)d_ws;
    _Float16* xb    = (_Float16*)(ws);                       // 8 MB  [4096][1024]
    _Float16* Vt    = (_Float16*)(ws);                       // aliases xb (xb dead after qkv GEMM)
    _Float16* Wqkvt = (_Float16*)(ws + ((size_t)8  << 20));  // 6 MB  [3072][1024]
    _Float16* Woutt = (_Float16*)(ws + ((size_t)14 << 20));  // 2 MB  [1024][1024]
    _Float16* Qh    = (_Float16*)(ws + ((size_t)16 << 20));  // 8 MB  [64][1024][64]
    _Float16* Kh    = (_Float16*)(ws + ((size_t)24 << 20));  // 8 MB
    _Float16* Vh    = (_Float16*)(ws + ((size_t)32 << 20));  // 8 MB
    _Float16* attO  = (_Float16*)(ws + ((size_t)40 << 20));  // 8 MB  [4096][1024]
    // total 48 MB

    // 1. convert / transpose weights & activations to f16
    cvt_f32_f16<<<2048, 256, 0, stream>>>(x, xb, 4096 * 1024 / 8);
    transpose_f32_to_f16<<<dim3(48, 16), 256, 0, stream>>>(Wqkv, Wqkvt, 1024, 3072);
    transpose_f32_to_f16<<<dim3(16, 16), 256, 0, stream>>>(Wout, Woutt, 1024, 1024);

    // 2. qkv GEMM (pipelined 256x256) with K/Q/V head-scatter epilogue
    gemm256<1><<<dim3(12, 16), 512, 0, stream>>>(
        xb, Wqkvt, bqkv, nullptr, Kh, Qh, Vh, 4096, 3072, 1024);

    // 3. V -> V^T per head (writes Vt over the now-dead xb region)
    transpose_f16<<<dim3(1, 16, 64), 256, 0, stream>>>(Vh, Vt, 1024, 64);

    // 4. flash attention
    attn_kernel<<<1024, 256, 0, stream>>>(Qh, Kh, Vt, attO);

    // 5. output projection (validated 2-phase 128x128 path)
    gemm_f16<0><<<dim3(8, 32), 256, 0, stream>>>(
        attO, Woutt, bout, out, nullptr, nullptr, nullptr, 4096, 1024, 1024);
}

// Round 9
// 184.451 us; speedup vs baseline: 1.1457x; 1.0352x over previous
//
#include <hip/hip_runtime.h>
#include <hip/hip_bf16.h>
#include <cstddef>
#include <cmath>

// Problem constants: B=4, N=1024, H=16, hd=64, EMB=1024, M=B*N=4096
// split order in reference: K, Q, V (cols 0..1023 = K, 1024..2047 = Q, 2048.. = V)

typedef _Float16 f16x4 __attribute__((ext_vector_type(4)));
typedef _Float16 f16x8 __attribute__((ext_vector_type(8)));
typedef __fp16   fp16x2r __attribute__((ext_vector_type(2)));   // cvt_pkrtz return type
typedef float    f32x4 __attribute__((ext_vector_type(4)));

#define LOG2E 1.4426950408889634f

// async global->LDS, 16B per lane. LDS dest: wave-uniform base + lane*16.
__device__ __forceinline__ void gload_lds16(const void* g, void* l) {
    __builtin_amdgcn_global_load_lds(
        (const __attribute__((address_space(1))) unsigned int*)g,
        (__attribute__((address_space(3))) unsigned int*)l, 16, 0, 0);
}

// ---------------------------------------------------------------------------
// prep: fused {x f32->f16 cvt | Wqkv transpose | Wout transpose} by block range.
// blocks 0..2047: cvt (8 elems/thread); 2048..2815: Wqkv^T (48x16 tiles);
// 2816..3071: Wout^T (16x16 tiles).
__device__ __forceinline__ void transpose_tile_f32f16(
    const float* __restrict__ in, _Float16* __restrict__ out,
    int R, int C, int cx, int cy, int t, float (*tile)[65])
{
    int r0 = cy * 64, c0 = cx * 64;
#pragma unroll
    for (int p = 0; p < 4; ++p) {
        int lin = p * 256 + t;
        int row = lin >> 4;
        int c4 = (lin & 15) * 4;
        float4 v = *(const float4*)(in + (size_t)(r0 + row) * C + c0 + c4);
        tile[row][c4] = v.x; tile[row][c4 + 1] = v.y;
        tile[row][c4 + 2] = v.z; tile[row][c4 + 3] = v.w;
    }
    __syncthreads();
#pragma unroll
    for (int p = 0; p < 2; ++p) {
        int lin = p * 256 + t;
        int oc = lin >> 3;
        int ch = (lin & 7) * 8;
        f16x8 o;
#pragma unroll
        for (int e = 0; e < 8; ++e) o[e] = (_Float16)tile[ch + e][oc];
        *(f16x8*)(out + (size_t)(c0 + oc) * R + r0 + ch) = o;
    }
}

__global__ __launch_bounds__(256) void prep(
    const float* __restrict__ x, _Float16* __restrict__ xb,
    const float* __restrict__ Wqkv, _Float16* __restrict__ Wqkvt,
    const float* __restrict__ Wout, _Float16* __restrict__ Woutt)
{
    __shared__ float tile[64][65];
    int bid = blockIdx.x, t = threadIdx.x;
    if (bid < 2048) {
        int i = bid * 256 + t;
        const float4* p = (const float4*)x;
        float4 v0 = p[i * 2], v1 = p[i * 2 + 1];
        f16x8 o;
        o[0] = (_Float16)v0.x; o[1] = (_Float16)v0.y; o[2] = (_Float16)v0.z; o[3] = (_Float16)v0.w;
        o[4] = (_Float16)v1.x; o[5] = (_Float16)v1.y; o[6] = (_Float16)v1.z; o[7] = (_Float16)v1.w;
        *(f16x8*)(xb + (size_t)i * 8) = o;
    } else if (bid < 2816) {
        int id = bid - 2048;                    // 768 tiles: 48 c x 16 r
        transpose_tile_f32f16(Wqkv, Wqkvt, 1024, 3072, id % 48, id / 48, t, tile);
    } else {
        int id = bid - 2816;                    // 256 tiles: 16 c x 16 r
        transpose_tile_f32f16(Wout, Woutt, 1024, 1024, id % 16, id / 16, t, tile);
    }
}

// ---------------------------------------------------------------------------
// gemm256: 256x256 tile, BK=32, 3-stage LDS pipeline with COUNTED vmcnt
// (T3+T4), T2 XOR-swizzle, T5 setprio, T1 XCD chunking. 512 thr = 8 waves
// (2M x 4N). EPI=0: fp32 out + bias. EPI=1: qkv scatter (K/Q head-major,
// V directly TRANSPOSED into Vt[bh][d][pos] - per-lane f16x4 over j).
template <int EPI>
__global__ __launch_bounds__(512, 2) void gemm256(
    const _Float16* __restrict__ A, const _Float16* __restrict__ Bt,
    const float* __restrict__ bias, float* __restrict__ Cout,
    _Float16* __restrict__ Kh, _Float16* __restrict__ Qh, _Float16* __restrict__ Vtd,
    int M, int Nn, int Kk)
{
    __shared__ _Float16 As[3][256 * 32];   // 48 KB
    __shared__ _Float16 Bs[3][256 * 32];   // 48 KB

    int lin = blockIdx.y * gridDim.x + blockIdx.x;
    int nwg = gridDim.x * gridDim.y;
    int lin2 = (lin & 7) * (nwg >> 3) + (lin >> 3);
    int bx = lin2 % gridDim.x, by = lin2 / gridDim.x;
    int m0 = by * 256, n0 = bx * 256;

    int tid = threadIdx.x, lane = tid & 63, wid = tid >> 6;
    int wm = wid >> 2, wn = wid & 3;
    int lr = lane & 15, lg = lane >> 4;

    int srow = tid >> 2;
    int scol = ((tid & 3) * 8) ^ ((srow & 6) << 2);
    const _Float16* pa0 = A  + (size_t)(m0 + srow) * Kk + scol;
    const _Float16* pa1 = A  + (size_t)(m0 + 128 + srow) * Kk + scol;
    const _Float16* pb0 = Bt + (size_t)(n0 + srow) * Kk + scol;
    const _Float16* pb1 = Bt + (size_t)(n0 + 128 + srow) * Kk + scol;
    int d0 = (wid * 64) * 8;
    int d1 = (512 + wid * 64) * 8;

    f32x4 acc[8][4] = {};
    const int NIT = Kk >> 5;

    gload_lds16(pa0, &As[0][d0]); gload_lds16(pa1, &As[0][d1]);
    gload_lds16(pb0, &Bs[0][d0]); gload_lds16(pb1, &Bs[0][d1]);
    gload_lds16(pa0 + 32, &As[1][d0]); gload_lds16(pa1 + 32, &As[1][d1]);
    gload_lds16(pb0 + 32, &Bs[1][d0]); gload_lds16(pb1 + 32, &Bs[1][d1]);

    for (int i = 0; i < NIT; ++i) {
        const _Float16* Ab = &As[i % 3][0];
        const _Float16* Bb = &Bs[i % 3][0];
        int sb = (i + 2) % 3;
        int ks = (i + 2 < NIT) ? (i + 2) * 32 : 0;

        asm volatile("s_waitcnt vmcnt(4)" ::: "memory");
        __builtin_amdgcn_s_barrier();

        f16x8 bf[4], af[4];
#pragma unroll
        for (int nf = 0; nf < 4; ++nf) {
            int rn = wn * 64 + nf * 16 + lr;
            bf[nf] = *(const f16x8*)&Bb[rn * 32 + ((lg * 8) ^ ((rn & 6) << 2))];
        }
#pragma unroll
        for (int mf = 0; mf < 4; ++mf) {
            int ra = wm * 128 + mf * 16 + lr;
            af[mf] = *(const f16x8*)&Ab[ra * 32 + ((lg * 8) ^ ((ra & 6) << 2))];
        }
        gload_lds16(pa0 + ks, &As[sb][d0]);
        gload_lds16(pa1 + ks, &As[sb][d1]);
        asm volatile("s_waitcnt lgkmcnt(0)" ::: "memory");
        __builtin_amdgcn_sched_barrier(0);
        __builtin_amdgcn_s_setprio(1);
#pragma unroll
        for (int mf = 0; mf < 4; ++mf)
#pragma unroll
            for (int nf = 0; nf < 4; ++nf)
                acc[mf][nf] = __builtin_amdgcn_mfma_f32_16x16x32_f16(
                    af[mf], bf[nf], acc[mf][nf], 0, 0, 0);
        __builtin_amdgcn_s_setprio(0);

#pragma unroll
        for (int mf = 0; mf < 4; ++mf) {
            int ra = wm * 128 + 64 + mf * 16 + lr;
            af[mf] = *(const f16x8*)&Ab[ra * 32 + ((lg * 8) ^ ((ra & 6) << 2))];
        }
        gload_lds16(pb0 + ks, &Bs[sb][d0]);
        gload_lds16(pb1 + ks, &Bs[sb][d1]);
        asm volatile("s_waitcnt lgkmcnt(0)" ::: "memory");
        __builtin_amdgcn_sched_barrier(0);
        __builtin_amdgcn_s_setprio(1);
#pragma unroll
        for (int mf = 0; mf < 4; ++mf)
#pragma unroll
            for (int nf = 0; nf < 4; ++nf)
                acc[4 + mf][nf] = __builtin_amdgcn_mfma_f32_16x16x32_f16(
                    af[mf], bf[nf], acc[4 + mf][nf], 0, 0, 0);
        __builtin_amdgcn_s_setprio(0);
    }

    // epilogue: C/D frag layout col = lane&15, row = (lane>>4)*4 + j
#pragma unroll
    for (int mh = 0; mh < 2; ++mh)
#pragma unroll
        for (int mf = 0; mf < 4; ++mf) {
            int gr0 = m0 + wm * 128 + mh * 64 + mf * 16 + lg * 4;   // j=0..3 consecutive
            int bb = gr0 >> 10, pos = gr0 & 1023;
#pragma unroll
            for (int nf = 0; nf < 4; ++nf) {
                int gc = n0 + wn * 64 + nf * 16 + lr;
                float bv = bias[gc];
                const f32x4& a = acc[mh * 4 + mf][nf];
                if constexpr (EPI == 0) {
#pragma unroll
                    for (int j = 0; j < 4; ++j)
                        Cout[(size_t)(gr0 + j) * Nn + gc] = a[j] + bv;
                } else {
                    int sec = gc >> 10, idx = gc & 1023;
                    int h = idx >> 6, d = idx & 63;
                    if (sec == 2) {
                        // V transposed: Vt[bh][d][pos], 4 consecutive pos per lane
                        f16x4 w;
#pragma unroll
                        for (int j = 0; j < 4; ++j) w[j] = (_Float16)(a[j] + bv);
                        *(f16x4*)&Vtd[(((size_t)(bb * 16 + h)) * 64 + d) * 1024 + pos] = w;
                    } else {
                        size_t base = (((size_t)(bb * 16 + h)) * 1024 + pos) * 64 + d;
                        if (sec == 0) {
#pragma unroll
                            for (int j = 0; j < 4; ++j)
                                Kh[base + (size_t)j * 64] = (_Float16)(a[j] + bv);
                        } else {
#pragma unroll
                            for (int j = 0; j < 4; ++j)
                                Qh[base + (size_t)j * 64] = (_Float16)((a[j] + bv) * (0.125f * LOG2E));
                        }
                    }
                }
            }
        }
}

// ---------------------------------------------------------------------------
// f16 MFMA GEMM (2-phase dbuf, validated) — output projection.
template <int EPI>
__global__ __launch_bounds__(256) void gemm_f16(
    const _Float16* __restrict__ A, const _Float16* __restrict__ Bt,
    const float* __restrict__ bias, float* __restrict__ Cout,
    int M, int Nn, int Kk)
{
    __shared__ _Float16 As[2][128 * 64];
    __shared__ _Float16 Bs[2][128 * 64];

    int lin = blockIdx.y * gridDim.x + blockIdx.x;
    int nwg = gridDim.x * gridDim.y;
    int lin2 = (lin & 7) * (nwg >> 3) + (lin >> 3);
    int bx = lin2 % gridDim.x, by = lin2 / gridDim.x;
    int m0 = by * 128, n0 = bx * 128;

    int t = threadIdx.x, lane = t & 63, wid = t >> 6;
    int wr = (wid >> 1) * 64, wc = (wid & 1) * 64;
    int lr = lane & 15, lg = lane >> 4;

    f32x4 acc[4][4] = {};
    int nt = Kk >> 6;

#pragma unroll
    for (int p = 0; p < 4; ++p) {
        int c = p * 256 + t;
        int row = c >> 3, col = (c & 7) * 8;
        int ubase = (p * 256 + wid * 64) * 8;
        gload_lds16(A  + (size_t)(m0 + row) * Kk + col, &As[0][ubase]);
        gload_lds16(Bt + (size_t)(n0 + row) * Kk + col, &Bs[0][ubase]);
    }
    __syncthreads();

    for (int tt = 0; tt < nt; ++tt) {
        int cur = tt & 1;
        if (tt + 1 < nt) {
            int k0 = (tt + 1) * 64;
#pragma unroll
            for (int p = 0; p < 4; ++p) {
                int c = p * 256 + t;
                int row = c >> 3, col = (c & 7) * 8;
                int ubase = (p * 256 + wid * 64) * 8;
                gload_lds16(A  + (size_t)(m0 + row) * Kk + k0 + col, &As[cur ^ 1][ubase]);
                gload_lds16(Bt + (size_t)(n0 + row) * Kk + k0 + col, &Bs[cur ^ 1][ubase]);
            }
        }
        const _Float16* Ac = &As[cur][0];
        const _Float16* Bc = &Bs[cur][0];
#pragma unroll
        for (int kk = 0; kk < 2; ++kk) {
            f16x8 af[4], bfr[4];
#pragma unroll
            for (int i = 0; i < 4; ++i) {
                af[i]  = *(const f16x8*)&Ac[(wr + i * 16 + lr) * 64 + kk * 32 + lg * 8];
                bfr[i] = *(const f16x8*)&Bc[(wc + i * 16 + lr) * 64 + kk * 32 + lg * 8];
            }
#pragma unroll
            for (int i = 0; i < 4; ++i)
#pragma unroll
                for (int jn = 0; jn < 4; ++jn)
                    acc[i][jn] = __builtin_amdgcn_mfma_f32_16x16x32_f16(
                        af[i], bfr[jn], acc[i][jn], 0, 0, 0);
        }
        __syncthreads();
    }

#pragma unroll
    for (int i = 0; i < 4; ++i)
#pragma unroll
        for (int jn = 0; jn < 4; ++jn) {
            int gc = n0 + wc + jn * 16 + lr;
            float bv = bias[gc];
#pragma unroll
            for (int j = 0; j < 4; ++j) {
                int gr = m0 + wr + i * 16 + lg * 4 + j;
                Cout[(size_t)gr * Nn + gc] = acc[i][jn][j] + bv;
            }
        }
}

// ---------------------------------------------------------------------------
// Flash attention v4: swapped QK^T + dbuf K/V staging + unroll-2 (static buf
// indices), cvt_pkrtz P-pack, T13 skip-rescale (THR=0, exact), T5 setprio.
__global__ __launch_bounds__(256) void attn_kernel(
    const _Float16* __restrict__ Qh, const _Float16* __restrict__ Kh,
    const _Float16* __restrict__ Vt, _Float16* __restrict__ attO)
{
    __shared__ _Float16 Ks[2][64 * 64];
    __shared__ _Float16 Vs[2][64 * 64];
    __shared__ _Float16 Pl[4][16 * 64];

    int wg = blockIdx.x;
    int swz = (wg & 7) * 128 + (wg >> 3);
    int bh = swz >> 4, qt = swz & 15;
    int b = bh >> 4, h = bh & 15;

    int tid = threadIdx.x;
    int wid = tid >> 6, lane = tid & 63;
    int lr = lane & 15, lg = lane >> 4;
    int q0 = qt * 64 + wid * 16;
    const _Float16* Qb = Qh + (size_t)bh * (1024 * 64);
    const _Float16* Kb = Kh + (size_t)bh * (1024 * 64);
    const _Float16* Vb = Vt + (size_t)bh * (64 * 1024);

    int c0 = tid, c1 = 256 + tid;
    int r0 = c0 >> 3, sc0 = ((c0 & 7) * 16) ^ ((r0 & 7) << 4);
    int r1 = c1 >> 3, sc1 = ((c1 & 7) * 16) ^ ((r1 & 7) << 4);
    int ub0 = (wid * 64) * 8, ub1 = (256 + wid * 64) * 8;

    f16x8 qf0 = *(const f16x8*)(Qb + (size_t)(q0 + lr) * 64 + lg * 8);
    f16x8 qf1 = *(const f16x8*)(Qb + (size_t)(q0 + lr) * 64 + 32 + lg * 8);

    float m = -1e30f, l = 0.f;
    f32x4 o[4] = {};
    int xr = (lr & 7) << 4;
    // loop-invariant LDS byte offsets
    int ko0 = lr * 128 + ((lg * 16) ^ xr);          // K/V row base, frag 0
    int ko1 = lr * 128 + ((64 + lg * 16) ^ xr);     // frag 1
    char* prow = (char*)&Pl[wid][lr * 64];

    gload_lds16(Kb + (size_t)r0 * 64 + (sc0 >> 1), &Ks[0][ub0]);
    gload_lds16(Kb + (size_t)r1 * 64 + (sc1 >> 1), &Ks[0][ub1]);
    gload_lds16(Vb + (size_t)r0 * 1024 + (sc0 >> 1), &Vs[0][ub0]);
    gload_lds16(Vb + (size_t)r1 * 1024 + (sc1 >> 1), &Vs[0][ub1]);
    __syncthreads();

#pragma unroll 2
    for (int t = 0; t < 16; ++t) {
        int cur = t & 1;                    // compile-time under unroll-2
        if (t < 15) {
            int kn = (t + 1) * 64;
            gload_lds16(Kb + (size_t)(kn + r0) * 64 + (sc0 >> 1), &Ks[cur ^ 1][ub0]);
            gload_lds16(Kb + (size_t)(kn + r1) * 64 + (sc1 >> 1), &Ks[cur ^ 1][ub1]);
            gload_lds16(Vb + (size_t)r0 * 1024 + kn + (sc0 >> 1), &Vs[cur ^ 1][ub0]);
            gload_lds16(Vb + (size_t)r1 * 1024 + kn + (sc1 >> 1), &Vs[cur ^ 1][ub1]);
        }
        const char* Kc = (const char*)&Ks[cur][0];
        const char* Vc = (const char*)&Vs[cur][0];

        // QK^T: S[k][q], k = kb*16 + lg*4 + j, q = lr
        f32x4 s[4] = {};
        __builtin_amdgcn_s_setprio(1);
#pragma unroll
        for (int kb = 0; kb < 4; ++kb) {
            f16x8 kf0 = *(const f16x8*)(Kc + kb * 2048 + ko0);
            f16x8 kf1 = *(const f16x8*)(Kc + kb * 2048 + ko1);
            s[kb] = __builtin_amdgcn_mfma_f32_16x16x32_f16(kf0, qf0, s[kb], 0, 0, 0);
            s[kb] = __builtin_amdgcn_mfma_f32_16x16x32_f16(kf1, qf1, s[kb], 0, 0, 0);
        }
        __builtin_amdgcn_s_setprio(0);

        // row max (in-lane tree + 2 cross-group shfl)
        float a0 = fmaxf(fmaxf(s[0][0], s[0][1]), fmaxf(s[0][2], s[0][3]));
        float a1 = fmaxf(fmaxf(s[1][0], s[1][1]), fmaxf(s[1][2], s[1][3]));
        float a2 = fmaxf(fmaxf(s[2][0], s[2][1]), fmaxf(s[2][2], s[2][3]));
        float a3 = fmaxf(fmaxf(s[3][0], s[3][1]), fmaxf(s[3][2], s[3][3]));
        float pmax = fmaxf(fmaxf(a0, a1), fmaxf(a2, a3));
        pmax = fmaxf(pmax, __shfl_xor(pmax, 16));
        pmax = fmaxf(pmax, __shfl_xor(pmax, 32));

        // T13 (THR=0, exact): rescale only when the running max actually grows
        if (!__all(pmax <= m)) {
            float mnew = fmaxf(m, pmax);
            float corr = exp2f(m - mnew);
            l *= corr;
#pragma unroll
            for (int db = 0; db < 4; ++db)
#pragma unroll
                for (int j = 0; j < 4; ++j) o[db][j] *= corr;
            m = mnew;
        }
#pragma unroll
        for (int kb = 0; kb < 4; ++kb)
#pragma unroll
            for (int j = 0; j < 4; ++j)
                s[kb][j] = exp2f(s[kb][j] - m);
        float rr0 = (s[0][0] + s[0][1]) + (s[0][2] + s[0][3]);
        float rr1 = (s[1][0] + s[1][1]) + (s[1][2] + s[1][3]);
        float rr2 = (s[2][0] + s[2][1]) + (s[2][2] + s[2][3]);
        float rr3 = (s[3][0] + s[3][1]) + (s[3][2] + s[3][3]);
        float rs = (rr0 + rr1) + (rr2 + rr3);
        rs += __shfl_xor(rs, 16);
        rs += __shfl_xor(rs, 32);
        l += rs;

        // P -> f16 via cvt_pkrtz (packed words), 4x 8B LDS writes
#pragma unroll
        for (int kb = 0; kb < 4; ++kb) {
            union { fp16x2r hp[2]; uint2 u; } cv;
            cv.hp[0] = __builtin_amdgcn_cvt_pkrtz(s[kb][0], s[kb][1]);
            cv.hp[1] = __builtin_amdgcn_cvt_pkrtz(s[kb][2], s[kb][3]);
            *(uint2*)(prow + ((kb * 32 + lg * 8) ^ xr)) = cv.u;
        }
        f16x8 pf0 = *(const f16x8*)(prow + ((lg * 16) ^ xr));
        f16x8 pf1 = *(const f16x8*)(prow + ((64 + lg * 16) ^ xr));

        // O^T[d][q] += mfma(V rows, P)
        __builtin_amdgcn_s_setprio(1);
#pragma unroll
        for (int db = 0; db < 4; ++db) {
            f16x8 vf0 = *(const f16x8*)(Vc + db * 2048 + ko0);
            f16x8 vf1 = *(const f16x8*)(Vc + db * 2048 + ko1);
            o[db] = __builtin_amdgcn_mfma_f32_16x16x32_f16(vf0, pf0, o[db], 0, 0, 0);
            o[db] = __builtin_amdgcn_mfma_f32_16x16x32_f16(vf1, pf1, o[db], 0, 0, 0);
        }
        __builtin_amdgcn_s_setprio(0);
        __syncthreads();
    }

    float li = 1.f / l;
#pragma unroll
    for (int db = 0; db < 4; ++db) {
        f16x4 w;
#pragma unroll
        for (int j = 0; j < 4; ++j) w[j] = (_Float16)(o[db][j] * li);
        *(f16x4*)(attO + ((size_t)b * 1024 + q0 + lr) * 1024 + h * 64 + db * 16 + lg * 4) = w;
    }
}

// ---------------------------------------------------------------------------
extern "C" void kernel_launch(void* const* d_in, const int* in_sizes, int n_in,
                              void* d_out, int out_size, void* d_ws, size_t ws_size,
                              hipStream_t stream)
{
    const float* x    = (const float*)d_in[0];   // [4096][1024]
    const float* Wqkv = (const float*)d_in[1];   // [1024][3072]
    const float* bqkv = (const float*)d_in[2];   // [3072]
    const float* Wout = (const float*)d_in[3];   // [1024][1024]
    const float* bout = (const float*)d_in[4];   // [1024]
    float* out = (float*)d_out;                  // [4096][1024]

    char* ws = (char*)d_ws;
    _Float16* xb    = (_Float16*)(ws);                       // 8 MB  [4096][1024]
    _Float16* Wqkvt = (_Float16*)(ws + ((size_t)8  << 20));  // 6 MB  [3072][1024]
    _Float16* Woutt = (_Float16*)(ws + ((size_t)14 << 20));  // 2 MB  [1024][1024]
    _Float16* Qh    = (_Float16*)(ws + ((size_t)16 << 20));  // 8 MB  [64][1024][64]
    _Float16* Kh    = (_Float16*)(ws + ((size_t)24 << 20));  // 8 MB
    _Float16* Vt    = (_Float16*)(ws + ((size_t)32 << 20));  // 8 MB  [64][64][1024] (direct from gemm256)
    _Float16* attO  = (_Float16*)(ws + ((size_t)40 << 20));  // 8 MB  [4096][1024]
    // total 48 MB

    // 1. fused convert + weight transposes (one launch)
    prep<<<3072, 256, 0, stream>>>(x, xb, Wqkv, Wqkvt, Wout, Woutt);

    // 2. qkv GEMM; scatters K/Q head-major and V directly transposed
    gemm256<1><<<dim3(12, 16), 512, 0, stream>>>(
        xb, Wqkvt, bqkv, nullptr, Kh, Qh, Vt, 4096, 3072, 1024);

    // 3. flash attention
    attn_kernel<<<1024, 256, 0, stream>>>(Qh, Kh, Vt, attO);

    // 4. output projection
    gemm_f16<0><<<dim3(8, 32), 256, 0, stream>>>(
        attO, Woutt, bout, out, 4096, 1024, 1024);
}